// Round 1
// 409.321 us; speedup vs baseline: 1.0984x; 1.0984x over previous
//
#include <hip/hip_runtime.h>
#include <stdint.h>

#define Bdim 4096
#define Sdim 64
#define Hdim 128

typedef __attribute__((ext_vector_type(8))) __bf16 bf16x8;
typedef __attribute__((ext_vector_type(4))) float f32x4;
typedef __attribute__((ext_vector_type(8))) unsigned short ushort8v;

// ---------- helpers ----------
__device__ __forceinline__ unsigned short f2bf(float f) {
  unsigned int u = __float_as_uint(f);
  u = u + 0x7fffu + ((u >> 16) & 1u);   // RNE; inputs finite
  return (unsigned short)(u >> 16);
}
__device__ __forceinline__ float bf2f(unsigned short s) {
  return __uint_as_float(((unsigned int)s) << 16);
}
__device__ __forceinline__ float sigm(float x) { return 1.0f / (1.0f + __expf(-x)); }
__device__ __forceinline__ float fast_tanh(float x) {
  float t = __expf(-2.0f * fabsf(x));
  float y = (1.0f - t) / (1.0f + t);
  return copysignf(y, x);
}
__device__ __forceinline__ ushort8v pack8(float4 v0, float4 v1) {
  ushort8v o;
  o[0] = f2bf(v0.x); o[1] = f2bf(v0.y); o[2] = f2bf(v0.z); o[3] = f2bf(v0.w);
  o[4] = f2bf(v1.x); o[5] = f2bf(v1.y); o[6] = f2bf(v1.z); o[7] = f2bf(v1.w);
  return o;
}

// async global->LDS, 16 B per lane (wave-uniform LDS base + lane*16 by HW)
__device__ __forceinline__ void glds16(const void* g, void* l) {
  auto* gp = reinterpret_cast<__attribute__((address_space(1))) unsigned int*>(
      reinterpret_cast<uintptr_t>(g));
  auto* lp = reinterpret_cast<__attribute__((address_space(3))) unsigned int*>(
      static_cast<uint32_t>(reinterpret_cast<uintptr_t>(l)));
  __builtin_amdgcn_global_load_lds(gp, lp, 16, 0, 0);
}

// stage one 128x128 bf16 weight (fragment-linear) into LDS; 1024 threads = 16 waves x 2 KB
__device__ __forceinline__ void stage_w(unsigned short* Ws, const unsigned short* wsrc,
                                        int w, int lane) {
#pragma unroll
  for (int i = 0; i < 2; ++i) {
    int chunk = w * 2 + i;             // 32 chunks of 1 KB
    glds16(wsrc + (size_t)chunk * 512 + lane * 8, Ws + chunk * 512);
  }
}

// one 128x128-tile GEMM step; wave (wr,wc) computes rows wr*32..+31, cols wc*32..+31
// A: XOR-swizzled LDS tile, W: fragment-linear weights; acc init = bias
__device__ __forceinline__ void gemm32(f32x4 acc[2][2], const unsigned short* A,
                                       const unsigned short* W,
                                       const float* __restrict__ biasN,
                                       int wr, int wc, int quad, int l15) {
  const int lane = quad * 16 + l15;
  bf16x8 a[2][4];
#pragma unroll
  for (int rt = 0; rt < 2; ++rt) {
    int row = wr * 32 + rt * 16 + l15;         // row & 15 == l15
#pragma unroll
    for (int k0 = 0; k0 < 4; ++k0)
      a[rt][k0] = *(const bf16x8*)&A[row * 128 + (((k0 << 2) | quad) ^ l15) * 8];
  }
#pragma unroll
  for (int ntl = 0; ntl < 2; ++ntl) {
    int nt = wc * 2 + ntl;
    float b = biasN[nt * 16 + l15];
    f32x4 c0 = {b, b, b, b};
    f32x4 c1 = c0;
#pragma unroll
    for (int k0 = 0; k0 < 4; ++k0) {
      bf16x8 bw = *(const bf16x8*)&W[((nt * 4 + k0) * 64 + lane) * 8];
      c0 = __builtin_amdgcn_mfma_f32_16x16x32_bf16(a[0][k0], bw, c0, 0, 0, 0);
      c1 = __builtin_amdgcn_mfma_f32_16x16x32_bf16(a[1][k0], bw, c1, 0, 0, 0);
    }
    acc[0][ntl] = c0;
    acc[1][ntl] = c1;
  }
}

// ---------- kernel 1: weights fp32 -> bf16 fragment-linear; b1s = sum_s b1 ----------
__global__ __launch_bounds__(256) void convert_kernel(
    const float* __restrict__ W1, const float* __restrict__ W3,
    const float* __restrict__ Wih, const float* __restrict__ Whh,
    const float* __restrict__ b1, unsigned short* __restrict__ wsW,
    float* __restrict__ b1s) {
  int cid = blockIdx.x * 256 + threadIdx.x;     // 0..274431
  int mat = cid >> 11;
  int within = cid & 2047;
  int f = within >> 6, lane = within & 63;
  int nt = f >> 2, k0 = f & 3;
  int o = nt * 16 + (lane & 15);
  int hb = k0 * 32 + (lane >> 4) * 8;
  const float* src;
  if (mat < 64)       src = W1 + (size_t)mat * 16384;
  else if (mat < 128) src = W3 + (size_t)(mat - 64) * 16384;
  else if (mat < 131) src = Wih + (size_t)(mat - 128) * 16384;
  else                src = Whh + (size_t)(mat - 131) * 16384;
  const float* p = src + o * 128 + hb;
  float4 v0 = *(const float4*)p;
  float4 v1 = *(const float4*)(p + 4);
  *(ushort8v*)(wsW + (size_t)cid * 8) = pack8(v0, v1);
  if (cid < 128) {
    float a = 0.0f;
    for (int s = 0; s < 64; ++s) a += b1[s * 128 + cid];
    b1s[cid] = a;
  }
}

// ---------- kernel 2: partial sums, double-buffered pipeline; 16 waves, 32x32 tiles ----
// grid (32 m-tiles of 128, 8 s-chunks); 1024 threads
__global__ __launch_bounds__(1024) void sum_kernel(
    const float* __restrict__ X, const unsigned short* __restrict__ wsW1,
    float* __restrict__ sumP) {
  __shared__ unsigned short Xs[2][128 * 128];   // 64 KB
  __shared__ unsigned short Ws[2][128 * 128];   // 64 KB
  const int t = threadIdx.x;
  const int lane = t & 63, w = t >> 6, quad = lane >> 4, l15 = lane & 15;
  const int wr = w >> 2, wc = w & 3;
  const int m0 = blockIdx.x * 128;
  const int sc = blockIdx.y;
  f32x4 acc[2][2] = {};

  // prologue: stage s-index 0 into buf0
  stage_w(Ws[0], wsW1 + (size_t)(sc * 8) * 16384, w, lane);
#pragma unroll
  for (int it = 0; it < 2; ++it) {
    int c = t + it * 1024;
    int r = c >> 4, bblk = c & 15;
    const float* p = X + (size_t)(m0 + r) * 8192 + (sc * 8) * 128 + bblk * 8;
    float4 v0 = *(const float4*)p;
    float4 v1 = *(const float4*)(p + 4);
    *(ushort8v*)(Xs[0] + r * 128 + (bblk ^ (r & 15)) * 8) = pack8(v0, v1);
  }
  __syncthreads();

  for (int si = 0; si < 8; ++si) {
    const int cur = si & 1;
    float4 xr[2][2];
    if (si < 7) {
      int s = sc * 8 + si + 1;
      stage_w(Ws[cur ^ 1], wsW1 + (size_t)s * 16384, w, lane);
#pragma unroll
      for (int it = 0; it < 2; ++it) {
        int c = t + it * 1024;
        int r = c >> 4, bblk = c & 15;
        const float* p = X + (size_t)(m0 + r) * 8192 + s * 128 + bblk * 8;
        xr[it][0] = *(const float4*)p;
        xr[it][1] = *(const float4*)(p + 4);
      }
    }
    // GEMM accumulate on current buffers
    {
      bf16x8 a[2][4];
#pragma unroll
      for (int rt = 0; rt < 2; ++rt) {
        int row = wr * 32 + rt * 16 + l15;
#pragma unroll
        for (int k0 = 0; k0 < 4; ++k0)
          a[rt][k0] = *(const bf16x8*)&Xs[cur][row * 128 + (((k0 << 2) | quad) ^ l15) * 8];
      }
#pragma unroll
      for (int ntl = 0; ntl < 2; ++ntl) {
        int nt = wc * 2 + ntl;
#pragma unroll
        for (int k0 = 0; k0 < 4; ++k0) {
          bf16x8 bw = *(const bf16x8*)&Ws[cur][((nt * 4 + k0) * 64 + lane) * 8];
          acc[0][ntl] = __builtin_amdgcn_mfma_f32_16x16x32_bf16(a[0][k0], bw, acc[0][ntl], 0, 0, 0);
          acc[1][ntl] = __builtin_amdgcn_mfma_f32_16x16x32_bf16(a[1][k0], bw, acc[1][ntl], 0, 0, 0);
        }
      }
    }
    if (si < 7) {
#pragma unroll
      for (int it = 0; it < 2; ++it) {
        int c = t + it * 1024;
        int r = c >> 4, bblk = c & 15;
        *(ushort8v*)(Xs[cur ^ 1] + r * 128 + (bblk ^ (r & 15)) * 8) = pack8(xr[it][0], xr[it][1]);
      }
    }
    __syncthreads();   // drains vmcnt (W ready) + lgkm (X converts visible); protects bufs
  }
  float* dst = sumP + (size_t)sc * 524288 + (size_t)m0 * 128;
#pragma unroll
  for (int rt = 0; rt < 2; ++rt)
#pragma unroll
    for (int ntl = 0; ntl < 2; ++ntl)
#pragma unroll
      for (int r = 0; r < 4; ++r) {
        int row = wr * 32 + rt * 16 + quad * 4 + r;
        int n = (wc * 2 + ntl) * 16 + l15;
        dst[(size_t)row * 128 + n] = acc[rt][ntl][r];
      }
}

// ---------- kernel 3: sumS = sum_c sumP[c] + b1s ----------
__global__ __launch_bounds__(256) void reduce_kernel(
    const float* __restrict__ sumP, const float* __restrict__ b1s,
    float* __restrict__ sumS) {
  int i = blockIdx.x * 256 + threadIdx.x;       // float4 index, 131072 total
  float4 acc = *(const float4*)(b1s + (i & 31) * 4);
#pragma unroll
  for (int c = 0; c < 8; ++c) {
    float4 v = *(const float4*)(sumP + (size_t)c * 524288 + (size_t)i * 4);
    acc.x += v.x; acc.y += v.y; acc.z += v.z; acc.w += v.w;
  }
  *(float4*)(sumS + (size_t)i * 4) = acc;
}

// ---------- kernel 4: fused state1..GRU..residual ----------
// 1024 threads = 16 waves (4 waves/SIMD), M-tile 128 x one s; wave tile 32x32.
// Weight LDS double-buffered; S2 in-place overwrite needs one extra barrier (col-split
// waves read all cols of their rows, so rows are no longer wave-private).
__global__ __launch_bounds__(1024) void fused_kernel(
    const float* __restrict__ X, const unsigned short* __restrict__ wsW,
    const float* __restrict__ b1, const float* __restrict__ b3,
    const float* __restrict__ bih, const float* __restrict__ bhh,
    const float* __restrict__ sumS, float* __restrict__ out) {
  __shared__ unsigned short Xs[128 * 128];      // 32 KB, lives whole kernel
  __shared__ unsigned short S2[128 * 128];      // 32 KB, state2 then state3
  __shared__ unsigned short Ws[2][128 * 128];   // 64 KB, double-buffered weights
  const int t = threadIdx.x;
  const int lane = t & 63, w = t >> 6, quad = lane >> 4, l15 = lane & 15;
  const int wr = w >> 2, wc = w & 3;
  const int m0 = blockIdx.x * 128;
  const int s = blockIdx.y;

  const unsigned short* Wptr[8] = {
      wsW + (size_t)s * 16384,          // W1[s]
      wsW + (size_t)(64 + s) * 16384,   // W3[s]
      wsW + (size_t)128 * 16384,        // Wih r
      wsW + (size_t)131 * 16384,        // Whh r
      wsW + (size_t)129 * 16384,        // Wih z
      wsW + (size_t)132 * 16384,        // Whh z
      wsW + (size_t)130 * 16384,        // Wih n
      wsW + (size_t)133 * 16384};       // Whh n

  stage_w(Ws[0], Wptr[0], w, lane);
#pragma unroll
  for (int it = 0; it < 2; ++it) {
    int c = t + it * 1024;
    int r = c >> 4, bblk = c & 15;
    const float* p = X + (size_t)(m0 + r) * 8192 + s * 128 + bblk * 8;
    float4 v0 = *(const float4*)p;
    float4 v1 = *(const float4*)(p + 4);
    *(ushort8v*)(Xs + r * 128 + (bblk ^ (r & 15)) * 8) = pack8(v0, v1);
  }
  __syncthreads();

  f32x4 gi[2][2], gh[2][2];
  float rg[2][2][4], zg[2][2][4];

  // ---- phase 0: state1 = X·W1^T + b1 ; state2 = sumS - state1 -> S2
  stage_w(Ws[1], Wptr[1], w, lane);
  gemm32(gi, Xs, Ws[0], b1 + s * 128, wr, wc, quad, l15);
  {
    const float* sp = sumS + (size_t)m0 * 128;
#pragma unroll
    for (int rt = 0; rt < 2; ++rt)
#pragma unroll
      for (int ntl = 0; ntl < 2; ++ntl)
#pragma unroll
        for (int r = 0; r < 4; ++r) {
          int rr = quad * 4 + r;                 // row & 15
          int row = wr * 32 + rt * 16 + rr;
          int n = (wc * 2 + ntl) * 16 + l15;
          float v = sp[(size_t)row * 128 + n] - gi[rt][ntl][r];
          S2[row * 128 + ((n >> 3) ^ rr) * 8 + (n & 7)] = f2bf(v);
        }
  }
  __syncthreads();
  // ---- phase 1: state3 = state2·W3^T + b3 -> S2 (in place; barrier before overwrite)
  stage_w(Ws[0], Wptr[2], w, lane);
  gemm32(gi, S2, Ws[1], b3 + s * 128, wr, wc, quad, l15);
  __syncthreads();   // all waves done reading state2 before overwrite
#pragma unroll
  for (int rt = 0; rt < 2; ++rt)
#pragma unroll
    for (int ntl = 0; ntl < 2; ++ntl)
#pragma unroll
      for (int r = 0; r < 4; ++r) {
        int rr = quad * 4 + r;
        int row = wr * 32 + rt * 16 + rr;
        int n = (wc * 2 + ntl) * 16 + l15;
        S2[row * 128 + ((n >> 3) ^ rr) * 8 + (n & 7)] = f2bf(gi[rt][ntl][r]);
      }
  __syncthreads();
  // ---- phase 2: gi_r = state3·Wih_r^T + bih_r
  stage_w(Ws[1], Wptr[3], w, lane);
  gemm32(gi, S2, Ws[0], bih + 0 * 128, wr, wc, quad, l15);
  __syncthreads();
  // ---- phase 3: gh_r = X·Whh_r^T + bhh_r ; r-gate
  stage_w(Ws[0], Wptr[4], w, lane);
  gemm32(gh, Xs, Ws[1], bhh + 0 * 128, wr, wc, quad, l15);
#pragma unroll
  for (int rt = 0; rt < 2; ++rt)
#pragma unroll
    for (int ntl = 0; ntl < 2; ++ntl)
#pragma unroll
      for (int r = 0; r < 4; ++r)
        rg[rt][ntl][r] = sigm(gi[rt][ntl][r] + gh[rt][ntl][r]);
  __syncthreads();
  // ---- phase 4: gi_z
  stage_w(Ws[1], Wptr[5], w, lane);
  gemm32(gi, S2, Ws[0], bih + 1 * 128, wr, wc, quad, l15);
  __syncthreads();
  // ---- phase 5: gh_z ; z-gate
  stage_w(Ws[0], Wptr[6], w, lane);
  gemm32(gh, Xs, Ws[1], bhh + 1 * 128, wr, wc, quad, l15);
#pragma unroll
  for (int rt = 0; rt < 2; ++rt)
#pragma unroll
    for (int ntl = 0; ntl < 2; ++ntl)
#pragma unroll
      for (int r = 0; r < 4; ++r)
        zg[rt][ntl][r] = sigm(gi[rt][ntl][r] + gh[rt][ntl][r]);
  __syncthreads();
  // ---- phase 6: gi_n
  stage_w(Ws[1], Wptr[7], w, lane);
  gemm32(gi, S2, Ws[0], bih + 2 * 128, wr, wc, quad, l15);
  __syncthreads();
  // ---- phase 7: gh_n ; n-gate, blend, residual, store
  gemm32(gh, Xs, Ws[1], bhh + 2 * 128, wr, wc, quad, l15);
#pragma unroll
  for (int rt = 0; rt < 2; ++rt)
#pragma unroll
    for (int ntl = 0; ntl < 2; ++ntl)
#pragma unroll
      for (int r = 0; r < 4; ++r) {
        int rr = quad * 4 + r;
        int row = wr * 32 + rt * 16 + rr;
        int n = (wc * 2 + ntl) * 16 + l15;
        float nv = fast_tanh(gi[rt][ntl][r] + rg[rt][ntl][r] * gh[rt][ntl][r]);
        float xv = bf2f(Xs[row * 128 + ((n >> 3) ^ rr) * 8 + (n & 7)]);
        float hn = (1.0f - zg[rt][ntl][r]) * nv + zg[rt][ntl][r] * xv;  // h_prev = X
        out[((size_t)(m0 + row) * 64 + s) * 128 + n] = xv + hn;         // out = X + h_new
      }
}

extern "C" void kernel_launch(void* const* d_in, const int* in_sizes, int n_in,
                              void* d_out, int out_size, void* d_ws, size_t ws_size,
                              hipStream_t stream) {
  const float* X   = (const float*)d_in[0];
  const float* W1  = (const float*)d_in[1];
  const float* b1  = (const float*)d_in[2];
  const float* W3  = (const float*)d_in[3];
  const float* b3  = (const float*)d_in[4];
  const float* Wih = (const float*)d_in[5];
  const float* bih = (const float*)d_in[6];
  const float* Whh = (const float*)d_in[7];
  const float* bhh = (const float*)d_in[8];
  float* out = (float*)d_out;

  // ws layout: [weights bf16 134*32KB][b1s 512B][sumS 2MB][sumP 16MB] ~= 22.2 MiB
  const size_t W_BYTES = (size_t)134 * 32768;
  unsigned short* wsW = (unsigned short*)d_ws;
  float* b1s  = (float*)((char*)d_ws + W_BYTES);
  float* sumS = (float*)((char*)d_ws + W_BYTES + 512);
  float* sumP = (float*)((char*)d_ws + W_BYTES + 512 + 2097152);

  convert_kernel<<<1072, 256, 0, stream>>>(W1, W3, Wih, Whh, b1, wsW, b1s);
  sum_kernel<<<dim3(32, 8), 1024, 0, stream>>>(X, wsW, sumP);
  reduce_kernel<<<512, 256, 0, stream>>>(sumP, b1s, sumS);
  fused_kernel<<<dim3(32, 64), 1024, 0, stream>>>(X, wsW, b1, b3, bih, bhh, sumS, out);
}